// Round 12
// baseline (29894.165 us; speedup 1.0000x reference)
//
#include <hip/hip_runtime.h>
#include <hip/hip_bf16.h>
#include <stdint.h>

// Dims
#define STEPS  200
#define KA     1792   // p(256) + ctx(512) + ah(1024)
#define KD     2560   // ctx(512) + ah(1024) + dh(1024)  (ring order)
#define NBLK   256
#define JLA    56     // KA/32 frag-iters (all LDS)
#define JLDL   76     // D frag-iters in LDS; 76..79 streamed from L2
#define JTD    80
#define WLDS_A (JLA*2*64*16)    // 114688 B
#define WLDS_D (JLDL*2*64*16)   // 155648 B
#define DSMEM  163840
#define SLOT   (64*2560)        // ring slot elements (bf16)
#define RELBASE 256             // u32 idx of release lines

using bf16 = __bf16;
typedef __bf16 bf16x8 __attribute__((ext_vector_type(8)));
typedef float  f32x4  __attribute__((ext_vector_type(4)));
typedef int    i32x4  __attribute__((ext_vector_type(4)));
typedef unsigned int       u32;
typedef unsigned long long u64;

union U16 { i32x4 i; bf16x8 v; float f[4]; u32 u[4]; };
union U2h { u32 u; bf16 h[2]; };

#define MFMA16(a,b,c) __builtin_amdgcn_mfma_f32_16x16x32_bf16((a),(b),(c),0,0,0)

#define GLD16(dst, addr) \
  asm volatile("global_load_dwordx4 %0, %1, off sc0 sc1" : "=&v"(dst) : "v"(addr))
#define WAITV0 \
  { asm volatile("s_waitcnt vmcnt(0)" ::: "memory"); __builtin_amdgcn_sched_barrier(0); }

// RMW-as-load poll primitive (coherence-point read; cannot be stale) — R9-proven
__device__ __forceinline__ u32 atom_peek(u32* p){
  u32 old;
  asm volatile("global_atomic_add %0, %1, %2, off sc0 sc1\n\t"
               "s_waitcnt vmcnt(0)"
               : "=v"(old) : "v"(p), "v"(0u) : "memory");
  return old;
}

__device__ __forceinline__ float sigf(float x){ return 1.f/(1.f+__expf(-x)); }
__device__ __forceinline__ float tanhf_(float x){
  float ax = fabsf(x);
  float e  = __expf(-2.f*ax);
  float t  = (1.f-e)/(1.f+e);
  return x < 0.f ? -t : t;
}

__device__ __forceinline__ void stu(u32* p, u32 v){
  __hip_atomic_store(p, v, __ATOMIC_RELAXED, __HIP_MEMORY_SCOPE_AGENT);
}

// ---------------- prologue conversion kernels ----------------
__global__ void cvt_kernel(const float* __restrict__ s, bf16* __restrict__ d, int n){
  int i = blockIdx.x*256 + threadIdx.x;
  if (i < n) d[i] = (bf16)s[i];
}
__global__ void cvt_pad_kernel(const float* __restrict__ s, bf16* __restrict__ d,
                               int rows, int cin, int cout){
  int i = blockIdx.x*256 + threadIdx.x;
  if (i >= rows*cout) return;
  int r = i / cout, c = i % cout;
  d[i] = (bf16)(c < cin ? s[(size_t)r*cin + c] : 0.f);
}
// A-weights: packed rows r = q*32 + g*8 + j  <-  orig g*1024 + q*8 + j ; K=[p768|ah1024]
__global__ void build_wa_pack(const float* __restrict__ Wiha, const float* __restrict__ Whha,
                              bf16* __restrict__ d){
  int i = blockIdx.x*256 + threadIdx.x;
  if (i >= 4096*1792) return;
  int r = i / 1792, k = i % 1792;
  int q = r >> 5, g = (r >> 3) & 3, j = r & 7;
  int orig = g*1024 + q*8 + j;
  float v = (k < 768) ? Wiha[(size_t)orig*768 + k] : Whha[(size_t)orig*1024 + (k - 768)];
  d[i] = (bf16)v;
}
// D-weights: packed rows (same permute); K-order [ctx512 | ah1024 | dh1024]
__global__ void build_wd_pack(const float* __restrict__ Wihd, const float* __restrict__ Whhd,
                              bf16* __restrict__ d){
  int i = blockIdx.x*256 + threadIdx.x;
  if (i >= 4096*2560) return;
  int r = i / 2560, k = i % 2560;
  int q = r >> 5, g = (r >> 3) & 3, j = r & 7;
  int orig = g*1024 + q*8 + j;
  float v;
  if (k < 512)        v = Wihd[(size_t)orig*1536 + 1024 + k];
  else if (k < 1536)  v = Wihd[(size_t)orig*1536 + (k - 512)];
  else                v = Whhd[(size_t)orig*1024 + (k - 1536)];
  d[i] = (bf16)v;
}
__global__ void build_wmelcat(const float* __restrict__ Wmel, const float* __restrict__ Wstop,
                              bf16* __restrict__ d){
  int i = blockIdx.x*256 + threadIdx.x;
  if (i >= 176*1536) return;
  int r = i / 1536, c = i % 1536;
  float v = (r < 160) ? Wmel[(size_t)r*1536 + c] : (r == 160 ? Wstop[c] : 0.f);
  d[i] = (bf16)v;
}
// packed biases + mel bias
__global__ void build_misc2(const float* biha, const float* bhha, float* biasa2,
                            const float* bihd, const float* bhhd, float* biasd2,
                            const float* bmel, const float* bstop, float* bias176){
  int i = blockIdx.x*256 + threadIdx.x;
  if (i < 4096){
    int q = i >> 5, g = (i >> 3) & 3, j = i & 7;
    int orig = g*1024 + q*8 + j;
    biasa2[i] = biha[orig] + bhha[orig];
  } else if (i < 8192){
    int r = i - 4096;
    int q = r >> 5, g = (r >> 3) & 3, j = r & 7;
    int orig = g*1024 + q*8 + j;
    biasd2[r] = bihd[orig] + bhhd[orig];
  } else if (i < 8192+176){
    int j = i - 8192;
    bias176[j] = (j < 160) ? bmel[j] : (j == 160 ? bstop[0] : 0.f);
  }
}
__global__ void build_decin(const float* __restrict__ inp, bf16* __restrict__ d){
  int i = blockIdx.x*256 + threadIdx.x;
  if (i >= 12800*96) return;
  int row = i / 96, c = i % 96;
  int s = row >> 6, b = row & 63;
  float v = 0.f;
  if (c < 80 && s > 0) v = inp[((size_t)b*400 + (2*s - 1))*80 + c];
  d[i] = (bf16)v;
}

// ---------------- generic MFMA GEMM (prologue/epilogue batched use) ----------------
template<int ACT, int OBF>
__global__ __launch_bounds__(256)
void gemm_k(const bf16* __restrict__ A, const bf16* __restrict__ Bm,
            const float* __restrict__ bias, float* __restrict__ Cf,
            bf16* __restrict__ Cb, int M, int N, int K, int MT)
{
  int wid = blockIdx.x*4 + (threadIdx.x >> 6);
  if (wid >= MT*(N >> 4)) return;
  int wm = wid % MT, wn = wid / MT;
  int l = threadIdx.x & 63, lo = l & 15, hi = l >> 4;
  const bf16* Bp = Bm + (size_t)(wn*16 + lo)*K + hi*8;
  const bf16* Ap = A  + (size_t)(wm*64 + lo)*K + hi*8;
  f32x4 acc0 = {0,0,0,0}, acc1 = {0,0,0,0}, acc2 = {0,0,0,0}, acc3 = {0,0,0,0};
  for (int k = 0; k < K; k += 32){
    bf16x8 bb = *(const bf16x8*)(Bp + k);
    bf16x8 a0 = *(const bf16x8*)(Ap + k);
    bf16x8 a1 = *(const bf16x8*)(Ap + (size_t)16*K + k);
    bf16x8 a2 = *(const bf16x8*)(Ap + (size_t)32*K + k);
    bf16x8 a3 = *(const bf16x8*)(Ap + (size_t)48*K + k);
    acc0 = MFMA16(a0, bb, acc0);
    acc1 = MFMA16(a1, bb, acc1);
    acc2 = MFMA16(a2, bb, acc2);
    acc3 = MFMA16(a3, bb, acc3);
  }
  int n = wn*16 + lo;
  float bv = bias ? bias[n] : 0.f;
  int m0 = wm*64 + hi*4;
  #pragma unroll
  for (int mt = 0; mt < 4; ++mt){
    f32x4 av = (mt==0)?acc0:(mt==1)?acc1:(mt==2)?acc2:acc3;
    #pragma unroll
    for (int r = 0; r < 4; ++r){
      float v = av[r] + bv;
      if (ACT) v = fmaxf(v, 0.f);
      size_t idx = (size_t)(m0 + mt*16 + r)*N + n;
      if (OBF) Cb[idx] = (bf16)v; else Cf[idx] = v;
    }
  }
}

// ---------------- grid barrier: RMW-polled (R9-proven) -----------------------------
__device__ __forceinline__ void gridbar(unsigned* cnt, unsigned nb){
  __syncthreads();
  const int tid = threadIdx.x;
  if (tid == 0)
    __hip_atomic_fetch_add(&cnt[(blockIdx.x >> 5)*16], 1u, __ATOMIC_RELAXED,
                           __HIP_MEMORY_SCOPE_AGENT);
  if (blockIdx.x == 0){
    if (tid < 64){
      const unsigned tgt = nb*32u;
      for (;;){
        bool ok = true;
        if (tid < 8) ok = (atom_peek(&cnt[tid*16]) >= tgt);
        if (__all(ok)) break;
        __builtin_amdgcn_s_sleep(4);
      }
      __hip_atomic_fetch_add(&cnt[RELBASE + tid*16], 1u, __ATOMIC_RELAXED,
                             __HIP_MEMORY_SCOPE_AGENT);
    }
  } else if (tid == 0){
    u32* rl = &cnt[RELBASE + (blockIdx.x & 63u)*16];
    while (atom_peek(rl) < nb)
      __builtin_amdgcn_s_sleep(4);
  }
  __syncthreads();
}

// ---------------- THE persistent scan kernel ---------------------------------------
// R12: FUSED-CELL GEMM. Packed weights: block q owns units q*8..q*8+8, all 4 gates
// (32 packed rows). Epilogue: gate tile -> LDS -> cell update (block-local state)
// -> h (bf16) written straight into the ring slot. No gate round trip, no phase-B
// cell work. B-blocks (0-63): q, energies, softmax, ctx only.
__global__ __launch_bounds__(256, 1)
void decoder_scan(const bf16* __restrict__ pall,
                  const bf16* __restrict__ Wa, const bf16* __restrict__ Wd2,
                  const float* __restrict__ biasa2, const float* __restrict__ biasd2,
                  const bf16* __restrict__ Wqb, const float* __restrict__ Wconv,
                  const float* __restrict__ Wloc, const float* __restrict__ vvp,
                  const float* __restrict__ pm, const bf16* __restrict__ enc_bf,
                  bf16* __restrict__ ring,
                  float* __restrict__ aC, float* __restrict__ dC,
                  bf16* __restrict__ proj, float* __restrict__ out_attn,
                  unsigned* __restrict__ cnt)
{
  extern __shared__ char smem[];
  const int tid = threadIdx.x;
  const int l = tid & 63, lo = l & 15, hi = l >> 4;
  const int wv = tid >> 6;

  const bool isA  = blockIdx.x < 128;
  const int  bq   = isA ? blockIdx.x : blockIdx.x - 128;
  const int  n0   = bq * 32;
  const int  K    = isA ? KA : KD;
  const int  JL   = isA ? JLA : JLDL;
  const bf16* Wg  = isA ? Wa : Wd2;
  const float* bias2 = isA ? biasa2 : biasd2;
  float* Cst = (isA ? aC : dC) + (size_t)bq*64*8;
  bf16* wlds = (bf16*)smem;

  // epilogue gate-stage: A reuses locb region; D uses dedicated 8KB after weights
  float* gb = isA ? (float*)(smem + WLDS_A + 2048) : (float*)(smem + WLDS_D);

  // phase-B LDS overlay (blocks 0-63; above A-weights)
  char* pb = smem + WLDS_A;
  bf16*  ahs   = (bf16*)pb;              // 2048 B
  float* locb  = (float*)(pb + 2048);    // 25600 (low 8KB doubles as gb)
  float* awl   = (float*)(pb + 27648);   // 1024
  float* qp    = (float*)(pb + 28672);   // 1024
  float* qv    = (float*)(pb + 29696);   // 512
  float* es    = (float*)(pb + 30208);   // 1024
  float* sred  = (float*)(pb + 31232);   // 64
  float* wlocT = (float*)(pb + 31296);   // 32x128 f32 (ends 162368)

  // ---- preload weights into LDS (fragment-major) ----
  for (int j = wv; j < JL; j += 4){
    #pragma unroll
    for (int t = 0; t < 2; ++t){
      bf16x8 v = *(const bf16x8*)(Wg + (size_t)(n0 + t*16 + lo)*K + j*32 + hi*8);
      *(bf16x8*)(wlds + ((size_t)(j*2 + t)*64 + l)*8) = v;
    }
  }

  unsigned nb = 0;

  if (blockIdx.x < 64){
    if (tid < 256) awl[tid] = 0.f;
    for (int it = tid; it < 4096; it += 256)
      wlocT[(it >> 7)*128 + (it & 127)] = Wloc[(it & 127)*32 + (it >> 7)];
  }
  __syncthreads();
  gridbar(cnt, ++nb);

  for (int i = 0; i <= STEPS; ++i){
    const bf16* slotPrev = ring + (size_t)i*SLOT;        // [ctx|ah|dh] of step i-1
    bf16*       slotCur  = ring + (size_t)(i+1)*SLOT;

    // ============== phase A: fused gate-GEMM + cell update ==============
    const bool work = isA ? (i < STEPS) : (i > 0);
    if (work){
      const int m0 = wv*16;
      const bf16* wl = wlds + (size_t)l*8;
      f32x4 acc0 = {0,0,0,0}, acc1 = {0,0,0,0};
      const bf16* Xp = slotPrev + (size_t)(m0 + lo)*2560 + hi*8;
      if (isA){
        const bf16* Pp = pall + ((size_t)i*64 + m0 + lo)*256 + hi*8;
        #pragma unroll
        for (int j = 0; j < 8; ++j){
          bf16x8 a  = *(const bf16x8*)(Pp + j*32);
          bf16x8 b0 = *(const bf16x8*)(wl + (size_t)(2*j    )*512);
          bf16x8 b1 = *(const bf16x8*)(wl + (size_t)(2*j + 1)*512);
          acc0 = MFMA16(a, b0, acc0);
          acc1 = MFMA16(a, b1, acc1);
        }
        #pragma unroll 8
        for (int j = 8; j < JLA; ++j){
          bf16x8 a  = *(const bf16x8*)(Xp + (j - 8)*32);
          bf16x8 b0 = *(const bf16x8*)(wl + (size_t)(2*j    )*512);
          bf16x8 b1 = *(const bf16x8*)(wl + (size_t)(2*j + 1)*512);
          acc0 = MFMA16(a, b0, acc0);
          acc1 = MFMA16(a, b1, acc1);
        }
      } else {
        #pragma unroll 8
        for (int j = 0; j < JLDL; ++j){
          bf16x8 a  = *(const bf16x8*)(Xp + j*32);
          bf16x8 b0 = *(const bf16x8*)(wl + (size_t)(2*j    )*512);
          bf16x8 b1 = *(const bf16x8*)(wl + (size_t)(2*j + 1)*512);
          acc0 = MFMA16(a, b0, acc0);
          acc1 = MFMA16(a, b1, acc1);
        }
        // streamed weight tail (L2-resident, packed rows)
        #pragma unroll
        for (int j = JLDL; j < JTD; ++j){
          bf16x8 a  = *(const bf16x8*)(Xp + j*32);
          bf16x8 b0 = *(const bf16x8*)(Wg + (size_t)(n0 +      lo)*K + j*32 + hi*8);
          bf16x8 b1 = *(const bf16x8*)(Wg + (size_t)(n0 + 16 + lo)*K + j*32 + hi*8);
          acc0 = MFMA16(a, b0, acc0);
          acc1 = MFMA16(a, b1, acc1);
        }
      }
      // stage gate tile to LDS: gb[batch][packed-col 0..32)
      #pragma unroll
      for (int r = 0; r < 4; ++r){
        gb[(m0 + hi*4 + r)*32 + lo]      = acc0[r];
        gb[(m0 + hi*4 + r)*32 + 16 + lo] = acc1[r];
      }
    }
    __syncthreads();
    if (work){
      // cell update: thread -> (batch b = tid>>2, unit pair jp = (tid&3)*2)
      const int b  = tid >> 2;
      const int jp = (tid & 3)*2;
      U2h hp;
      #pragma unroll
      for (int t = 0; t < 2; ++t){
        int j = jp + t;
        float gi = gb[b*32 +      j] + bias2[n0 +      j];
        float gf = gb[b*32 +  8 + j] + bias2[n0 +  8 + j];
        float gg = gb[b*32 + 16 + j] + bias2[n0 + 16 + j];
        float go = gb[b*32 + 24 + j] + bias2[n0 + 24 + j];
        float* cp = Cst + b*8 + j;
        float c = sigf(gf)*(*cp) + sigf(gi)*tanhf_(gg);
        float h = sigf(go)*tanhf_(c);
        *cp = c;
        hp.h[t] = (bf16)h;
      }
      const int u = bq*8 + jp;
      if (isA){
        stu((u32*)(slotCur + (size_t)b*2560 + 512 + u), hp.u);
      } else {
        stu((u32*)(slotCur + (size_t)b*2560 + 1536 + u), hp.u);
        *(u32*)(proj + ((size_t)(i-1)*64 + b)*1536 + u) = hp.u;   // dh -> proj (plain)
      }
    }
    __syncthreads();
    // conv1d(31) of previous alignment (B-blocks; reuses gb/locb region AFTER epilogue)
    if (blockIdx.x < 64 && i < STEPS){
      for (int it = tid; it < 6400; it += 256){
        int f = it & 31, tl = it >> 5;
        float s = 0.f;
        #pragma unroll
        for (int j = 0; j < 31; ++j){
          int tt = tl + j - 15;
          if ((unsigned)tt < 200u) s += awl[tt]*Wconv[f*31+j];
        }
        locb[tl*32 + f] = s;
      }
    }
    gridbar(cnt, ++nb);

    // =================== phase B: attention only (blocks 0-63) ===================
    if (blockIdx.x < 64 && i < STEPS){
      const int b = blockIdx.x;
      // stage ah(i) from slot (written by A-blocks in phase A)
      if (tid < 128)
        *(bf16x8*)(&ahs[tid*8]) = *(const bf16x8*)(slotCur + (size_t)b*2560 + 512 + tid*8);
      __syncthreads();
      // q = ah @ Wq^T
      {
        int a = tid & 127, hf = tid >> 7;
        const bf16* wr = Wqb + (size_t)a*1024 + hf*512;
        float s = 0.f;
        for (int k2 = 0; k2 < 512; k2 += 8){
          bf16x8 x = *(const bf16x8*)(&ahs[hf*512 + k2]);
          bf16x8 y = *(const bf16x8*)(wr + k2);
          #pragma unroll
          for (int e = 0; e < 8; ++e) s += (float)x[e]*(float)y[e];
        }
        qp[tid] = s;
      }
      __syncthreads();
      if (tid < 128) qv[tid] = qp[tid] + qp[tid+128];
      __syncthreads();
      // energies
      for (int tl = wv; tl < 200; tl += 4){
        const float* pmrow = pm + ((size_t)b*200 + tl)*128;
        const float* lrow  = locb + tl*32;
        float s = 0.f;
        #pragma unroll
        for (int half = 0; half < 2; ++half){
          int a = l + half*64;
          float x = qv[a] + pmrow[a];
          const float* wc = wlocT + a;
          #pragma unroll
          for (int f = 0; f < 32; ++f) x += lrow[f]*wc[f*128];
          s += vvp[a]*tanhf_(x);
        }
        #pragma unroll
        for (int o = 32; o; o >>= 1) s += __shfl_xor(s, o);
        if (l == 0) es[tl] = s;
      }
      __syncthreads();
      // softmax over 200
      {
        float e0 = (tid < 200) ? es[tid] : -3.0e38f;
        float m = e0;
        #pragma unroll
        for (int o = 32; o; o >>= 1) m = fmaxf(m, __shfl_xor(m, o));
        if (l == 0) sred[wv] = m;
        __syncthreads();
        m = fmaxf(fmaxf(sred[0],sred[1]), fmaxf(sred[2],sred[3]));
        float p = (tid < 200) ? __expf(e0 - m) : 0.f;
        float ss = p;
        #pragma unroll
        for (int o = 32; o; o >>= 1) ss += __shfl_xor(ss, o);
        __syncthreads();
        if (l == 0) sred[wv] = ss;
        __syncthreads();
        ss = sred[0]+sred[1]+sred[2]+sred[3];
        float aval = p / ss;
        if (tid < 200){
          awl[tid] = aval;
          out_attn[((size_t)b*200 + i)*200 + tid] = aval;
        }
      }
      __syncthreads();
      // context = align @ enc  -> slot i cols [0,512)
      {
        const u32* ep = (const u32*)(enc_bf + (size_t)b*102400) + tid;
        float x0=0.f, y0=0.f, x1=0.f, y1=0.f;
        #pragma unroll 8
        for (int t = 0; t < 200; t += 2){
          U2h w0; w0.u = ep[(size_t)t*256];
          U2h w1; w1.u = ep[(size_t)(t+1)*256];
          float al0 = awl[t], al1 = awl[t+1];
          x0 += al0*(float)w0.h[0]; y0 += al0*(float)w0.h[1];
          x1 += al1*(float)w1.h[0]; y1 += al1*(float)w1.h[1];
        }
        U2h cb; cb.h[0] = (bf16)(x0+x1); cb.h[1] = (bf16)(y0+y1);
        stu((u32*)(slotCur + (size_t)b*2560) + tid, cb.u);
        *((u32*)(proj + ((size_t)i*64 + b)*1536 + 1024) + tid) = cb.u;
      }
    }
    gridbar(cnt, ++nb);
  }
}

// ---------------- epilogue scatter -------------------------------------------------
__global__ void scatter_out(const float* __restrict__ mt_, float* __restrict__ out){
  int i = blockIdx.x*256 + threadIdx.x;
  const int NMEL = 12800*160;
  if (i < NMEL){
    int sb = i / 160, j = i % 160;
    int s = sb >> 6, b = sb & 63;
    int r = j / 80, mm = j % 80;
    out[((size_t)b*400 + 2*s + r)*80 + mm] = mt_[(size_t)sb*176 + j];
  } else if (i < NMEL + 12800){
    int sb = i - NMEL;
    int s = sb >> 6, b = sb & 63;
    float st = sigf(mt_[(size_t)sb*176 + 160]);
    float* so = out + 2048000;
    so[(size_t)b*400 + 2*s]     = st;
    so[(size_t)b*400 + 2*s + 1] = st;
  }
}

// ==================================================================================
extern "C" void kernel_launch(void* const* d_in, const int* in_sizes, int n_in,
                              void* d_out, int out_size, void* d_ws, size_t ws_size,
                              hipStream_t stream)
{
  const float* enc   = (const float*)d_in[0];
  const float* inp   = (const float*)d_in[1];
  const float* Wpre1 = (const float*)d_in[2];
  const float* bpre1 = (const float*)d_in[3];
  const float* Wpre2 = (const float*)d_in[4];
  const float* bpre2 = (const float*)d_in[5];
  const float* Wmem  = (const float*)d_in[6];
  const float* Wiha  = (const float*)d_in[7];
  const float* Whha  = (const float*)d_in[8];
  const float* biha  = (const float*)d_in[9];
  const float* bhha  = (const float*)d_in[10];
  const float* Wq    = (const float*)d_in[11];
  const float* Wconv = (const float*)d_in[12];
  const float* Wloc  = (const float*)d_in[13];
  const float* vv    = (const float*)d_in[14];
  const float* Wihd  = (const float*)d_in[15];
  const float* Whhd  = (const float*)d_in[16];
  const float* bihd  = (const float*)d_in[17];
  const float* bhhd  = (const float*)d_in[18];
  const float* Wmel  = (const float*)d_in[19];
  const float* bmel  = (const float*)d_in[20];
  const float* Wstop = (const float*)d_in[21];
  const float* bstop = (const float*)d_in[22];
  float* out = (float*)d_out;

  char* pp = (char*)d_ws;
  auto carve = [&](size_t bytes)->char*{
    char* r = (char*)(((uintptr_t)pp + 255) & ~(uintptr_t)255);
    pp = r + bytes;
    return r;
  };
  bf16*  enc_bf  = (bf16*) carve((size_t)64*200*512*2);
  float* pm      = (float*)carve((size_t)64*200*128*4);
  bf16*  decin   = (bf16*) carve((size_t)12800*96*2);
  bf16*  h1      = (bf16*) carve((size_t)12800*256*2);
  bf16*  pall    = (bf16*) carve((size_t)12800*256*2);
  bf16*  Wp1b    = (bf16*) carve((size_t)256*96*2);
  bf16*  Wp2b    = (bf16*) carve((size_t)256*256*2);
  bf16*  Wmemb   = (bf16*) carve((size_t)128*512*2);
  bf16*  Wqb     = (bf16*) carve((size_t)128*1024*2);
  bf16*  Wca     = (bf16*) carve((size_t)4096*KA*2);
  bf16*  Wcd2    = (bf16*) carve((size_t)4096*KD*2);
  bf16*  Wmc     = (bf16*) carve((size_t)176*1536*2);
  float* biasa2  = (float*)carve(4096*4);
  float* biasd2  = (float*)carve(4096*4);
  float* bias176 = (float*)carve(176*4);
  bf16*  proj    = (bf16*) carve((size_t)12800*1536*2);
  float* meltmp  = (float*)carve((size_t)12800*176*4);
  // zeroed-every-launch block: cell states + barrier counters
  float* aC  = (float*)carve((size_t)128*64*8*4);
  float* dC  = (float*)carve((size_t)128*64*8*4);
  unsigned* cnt = (unsigned*)carve(16384);
  size_t zbytes = (size_t)((char*)cnt + 16384 - (char*)aC);
  // write-once activation ring: 202 slots of [64][2560] bf16
  bf16*  ring = (bf16*)carve((size_t)202*SLOT*2);
  hipMemsetAsync(aC, 0, zbytes, stream);
  hipMemsetAsync(ring, 0, (size_t)2*SLOT*2, stream);   // zero slots -1 and 0 (dh(-1))

  // ---- prologue: conversions / packing ----
  cvt_kernel<<<(6553600+255)/256,256,0,stream>>>(enc,   enc_bf, 6553600);
  cvt_kernel<<<(131072+255)/256, 256,0,stream>>>(Wq,    Wqb,    131072);
  cvt_kernel<<<(65536+255)/256,  256,0,stream>>>(Wmem,  Wmemb,  65536);
  cvt_kernel<<<(65536+255)/256,  256,0,stream>>>(Wpre2, Wp2b,   65536);
  cvt_pad_kernel<<<(256*96+255)/256,256,0,stream>>>(Wpre1, Wp1b, 256, 80, 96);
  build_wa_pack<<<(4096*1792+255)/256,256,0,stream>>>(Wiha, Whha, Wca);
  build_wd_pack<<<(4096*2560+255)/256,256,0,stream>>>(Wihd, Whhd, Wcd2);
  build_wmelcat<<<(176*1536+255)/256,256,0,stream>>>(Wmel, Wstop, Wmc);
  build_misc2<<<(8368+255)/256,256,0,stream>>>(biha,bhha,biasa2, bihd,bhhd,biasd2,
                                               bmel,bstop,bias176);
  build_decin<<<(12800*96+255)/256,256,0,stream>>>(inp, decin);

  // ---- prologue: batched GEMMs ----
  gemm_k<1,1><<<800,256,0,stream>>>(decin, Wp1b, bpre1, nullptr, h1, 12800,256,96, 200);
  gemm_k<1,1><<<800,256,0,stream>>>(h1, Wp2b, bpre2, nullptr, pall, 12800,256,256, 200);
  gemm_k<0,0><<<400,256,0,stream>>>(enc_bf, Wmemb, nullptr, pm, nullptr, 12800,128,512, 200);

  // ---- the whole 200-step scan as ONE persistent kernel ----
  hipFuncSetAttribute((const void*)decoder_scan,
                      hipFuncAttributeMaxDynamicSharedMemorySize, DSMEM);
  float* out_attn = out + 2073600;
  decoder_scan<<<NBLK,256,DSMEM,stream>>>(pall, Wca, Wcd2, biasa2, biasd2,
                                          Wqb, Wconv, Wloc, vv, pm, enc_bf,
                                          ring, aC, dC,
                                          proj, out_attn, cnt);

  // ---- epilogue: mel/stop projection + scatter ----
  gemm_k<0,0><<<550,256,0,stream>>>(proj, Wmc, bias176, meltmp, nullptr, 12800,176,1536, 200);
  scatter_out<<<(12800*160+12800+255)/256,256,0,stream>>>(meltmp, out);
}

// Round 14
// 28539.401 us; speedup vs baseline: 1.0475x; 1.0475x over previous
//
#include <hip/hip_runtime.h>
#include <hip/hip_bf16.h>
#include <stdint.h>

// Dims
#define STEPS  200
#define KA     1792   // p(256) + ctx(512) + ah(1024)
#define KD     2560   // ctx(512) + ah(1024) + dh(1024)  (ring order)
#define SLOT   (64*2560)        // ring slot elements (bf16)

using bf16 = __bf16;
typedef __bf16 bf16x8 __attribute__((ext_vector_type(8)));
typedef float  f32x4  __attribute__((ext_vector_type(4)));
typedef unsigned int       u32;
typedef unsigned long long u64;

union U2h { u32 u; bf16 h[2]; };

#define MFMA16(a,b,c) __builtin_amdgcn_mfma_f32_16x16x32_bf16((a),(b),(c),0,0,0)

__device__ __forceinline__ float sigf(float x){ return 1.f/(1.f+__expf(-x)); }
__device__ __forceinline__ float tanhf_(float x){
  float ax = fabsf(x);
  float e  = __expf(-2.f*ax);
  float t  = (1.f-e)/(1.f+e);
  return x < 0.f ? -t : t;
}

// ---------------- prologue conversion kernels ----------------
__global__ void cvt_kernel(const float* __restrict__ s, bf16* __restrict__ d, int n){
  int i = blockIdx.x*256 + threadIdx.x;
  if (i < n) d[i] = (bf16)s[i];
}
__global__ void cvt_pad_kernel(const float* __restrict__ s, bf16* __restrict__ d,
                               int rows, int cin, int cout){
  int i = blockIdx.x*256 + threadIdx.x;
  if (i >= rows*cout) return;
  int r = i / cout, c = i % cout;
  d[i] = (bf16)(c < cin ? s[(size_t)r*cin + c] : 0.f);
}
// A-weights: packed rows r = q*32 + g*8 + j  <-  orig g*1024 + q*8 + j ; K=[p768|ah1024]
__global__ void build_wa_pack(const float* __restrict__ Wiha, const float* __restrict__ Whha,
                              bf16* __restrict__ d){
  int i = blockIdx.x*256 + threadIdx.x;
  if (i >= 4096*1792) return;
  int r = i / 1792, k = i % 1792;
  int q = r >> 5, g = (r >> 3) & 3, j = r & 7;
  int orig = g*1024 + q*8 + j;
  float v = (k < 768) ? Wiha[(size_t)orig*768 + k] : Whha[(size_t)orig*1024 + (k - 768)];
  d[i] = (bf16)v;
}
// D-weights: packed rows (same permute); K-order [ctx512 | ah1024 | dh1024]
__global__ void build_wd_pack(const float* __restrict__ Wihd, const float* __restrict__ Whhd,
                              bf16* __restrict__ d){
  int i = blockIdx.x*256 + threadIdx.x;
  if (i >= 4096*2560) return;
  int r = i / 2560, k = i % 2560;
  int q = r >> 5, g = (r >> 3) & 3, j = r & 7;
  int orig = g*1024 + q*8 + j;
  float v;
  if (k < 512)        v = Wihd[(size_t)orig*1536 + 1024 + k];
  else if (k < 1536)  v = Wihd[(size_t)orig*1536 + (k - 512)];
  else                v = Whhd[(size_t)orig*1024 + (k - 1536)];
  d[i] = (bf16)v;
}
__global__ void build_wmelcat(const float* __restrict__ Wmel, const float* __restrict__ Wstop,
                              bf16* __restrict__ d){
  int i = blockIdx.x*256 + threadIdx.x;
  if (i >= 176*1536) return;
  int r = i / 1536, c = i % 1536;
  float v = (r < 160) ? Wmel[(size_t)r*1536 + c] : (r == 160 ? Wstop[c] : 0.f);
  d[i] = (bf16)v;
}
// packed biases + mel bias + transposed Wloc
__global__ void build_misc2(const float* biha, const float* bhha, float* biasa2,
                            const float* bihd, const float* bhhd, float* biasd2,
                            const float* bmel, const float* bstop, float* bias176,
                            const float* Wloc, float* wlocT){
  int i = blockIdx.x*256 + threadIdx.x;
  if (i < 4096){
    int q = i >> 5, g = (i >> 3) & 3, j = i & 7;
    int orig = g*1024 + q*8 + j;
    biasa2[i] = biha[orig] + bhha[orig];
  } else if (i < 8192){
    int r = i - 4096;
    int q = r >> 5, g = (r >> 3) & 3, j = r & 7;
    int orig = g*1024 + q*8 + j;
    biasd2[r] = bihd[orig] + bhhd[orig];
  } else if (i < 8192+176){
    int j = i - 8192;
    bias176[j] = (j < 160) ? bmel[j] : (j == 160 ? bstop[0] : 0.f);
  } else if (i < 8192+176+4096){
    int t = i - 8368;                 // t = f*128 + a
    int f = t >> 7, a = t & 127;
    wlocT[t] = Wloc[a*32 + f];
  }
}
__global__ void build_decin(const float* __restrict__ inp, bf16* __restrict__ d){
  int i = blockIdx.x*256 + threadIdx.x;
  if (i >= 12800*96) return;
  int row = i / 96, c = i % 96;
  int s = row >> 6, b = row & 63;
  float v = 0.f;
  if (c < 80 && s > 0) v = inp[((size_t)b*400 + (2*s - 1))*80 + c];
  d[i] = (bf16)v;
}

// ---------------- generic MFMA GEMM (prologue/epilogue batched use) ----------------
template<int ACT, int OBF>
__global__ __launch_bounds__(256)
void gemm_k(const bf16* __restrict__ A, const bf16* __restrict__ Bm,
            const float* __restrict__ bias, float* __restrict__ Cf,
            bf16* __restrict__ Cb, int M, int N, int K, int MT)
{
  int wid = blockIdx.x*4 + (threadIdx.x >> 6);
  if (wid >= MT*(N >> 4)) return;
  int wm = wid % MT, wn = wid / MT;
  int l = threadIdx.x & 63, lo = l & 15, hi = l >> 4;
  const bf16* Bp = Bm + (size_t)(wn*16 + lo)*K + hi*8;
  const bf16* Ap = A  + (size_t)(wm*64 + lo)*K + hi*8;
  f32x4 acc0 = {0,0,0,0}, acc1 = {0,0,0,0}, acc2 = {0,0,0,0}, acc3 = {0,0,0,0};
  for (int k = 0; k < K; k += 32){
    bf16x8 bb = *(const bf16x8*)(Bp + k);
    bf16x8 a0 = *(const bf16x8*)(Ap + k);
    bf16x8 a1 = *(const bf16x8*)(Ap + (size_t)16*K + k);
    bf16x8 a2 = *(const bf16x8*)(Ap + (size_t)32*K + k);
    bf16x8 a3 = *(const bf16x8*)(Ap + (size_t)48*K + k);
    acc0 = MFMA16(a0, bb, acc0);
    acc1 = MFMA16(a1, bb, acc1);
    acc2 = MFMA16(a2, bb, acc2);
    acc3 = MFMA16(a3, bb, acc3);
  }
  int n = wn*16 + lo;
  float bv = bias ? bias[n] : 0.f;
  int m0 = wm*64 + hi*4;
  #pragma unroll
  for (int mt = 0; mt < 4; ++mt){
    f32x4 av = (mt==0)?acc0:(mt==1)?acc1:(mt==2)?acc2:acc3;
    #pragma unroll
    for (int r = 0; r < 4; ++r){
      float v = av[r] + bv;
      if (ACT) v = fmaxf(v, 0.f);
      size_t idx = (size_t)(m0 + mt*16 + r)*N + n;
      if (OBF) Cb[idx] = (bf16)v; else Cf[idx] = v;
    }
  }
}

// ---------------- K1: fused gate-GEMM + LSTM cell (per step) ----------------------
// 256 blocks x 256 thr. Blocks 0-127: attn-LSTM (step i, if doA). Blocks 128-255:
// dec-LSTM (step i-1, if doD). Packed weights (R12 layout, proven). Plain memory;
// coherence via kernel boundaries.
__global__ __launch_bounds__(256)
void gates_step(const bf16* __restrict__ pall,
                const bf16* __restrict__ Wa, const bf16* __restrict__ Wd2,
                const float* __restrict__ biasa2, const float* __restrict__ biasd2,
                const bf16* __restrict__ slotPrev, bf16* __restrict__ slotCur,
                float* __restrict__ aC, float* __restrict__ dC,
                bf16* __restrict__ proj, int i, int doA, int doD)
{
  const bool isA = blockIdx.x < 128;
  if (isA ? !doA : !doD) return;
  const int tid = threadIdx.x;
  const int l = tid & 63, lo = l & 15, hi = l >> 4;
  const int wv = tid >> 6;
  const int bq = isA ? blockIdx.x : blockIdx.x - 128;
  const int n0 = bq * 32;
  const int K  = isA ? KA : KD;
  const bf16* Wg = isA ? Wa : Wd2;
  const float* bias2 = isA ? biasa2 : biasd2;
  float* Cst = (isA ? aC : dC) + (size_t)bq*64*8;

  __shared__ float gb[64][33];   // +1 pad: conflict-free staging

  const int m0 = wv*16;
  const bf16* Wp0 = Wg + (size_t)(n0 +      lo)*K + hi*8;
  const bf16* Wp1 = Wg + (size_t)(n0 + 16 + lo)*K + hi*8;
  f32x4 acc0 = {0,0,0,0}, acc1 = {0,0,0,0};
  const bf16* Xp = slotPrev + (size_t)(m0 + lo)*2560 + hi*8;
  if (isA){
    const bf16* Pp = pall + ((size_t)i*64 + m0 + lo)*256 + hi*8;
    #pragma unroll
    for (int j = 0; j < 8; ++j){
      bf16x8 a  = *(const bf16x8*)(Pp + j*32);
      bf16x8 b0 = *(const bf16x8*)(Wp0 + j*32);
      bf16x8 b1 = *(const bf16x8*)(Wp1 + j*32);
      acc0 = MFMA16(a, b0, acc0);
      acc1 = MFMA16(a, b1, acc1);
    }
    #pragma unroll 8
    for (int j = 8; j < 56; ++j){
      bf16x8 a  = *(const bf16x8*)(Xp + (j - 8)*32);
      bf16x8 b0 = *(const bf16x8*)(Wp0 + j*32);
      bf16x8 b1 = *(const bf16x8*)(Wp1 + j*32);
      acc0 = MFMA16(a, b0, acc0);
      acc1 = MFMA16(a, b1, acc1);
    }
  } else {
    #pragma unroll 8
    for (int j = 0; j < 80; ++j){
      bf16x8 a  = *(const bf16x8*)(Xp + j*32);
      bf16x8 b0 = *(const bf16x8*)(Wp0 + j*32);
      bf16x8 b1 = *(const bf16x8*)(Wp1 + j*32);
      acc0 = MFMA16(a, b0, acc0);
      acc1 = MFMA16(a, b1, acc1);
    }
  }
  #pragma unroll
  for (int r = 0; r < 4; ++r){
    gb[m0 + hi*4 + r][lo]      = acc0[r];
    gb[m0 + hi*4 + r][16 + lo] = acc1[r];
  }
  __syncthreads();
  // cell update: thread -> (batch b = tid>>2, unit pair jp = (tid&3)*2)
  const int b  = tid >> 2;
  const int jp = (tid & 3)*2;
  U2h hp;
  #pragma unroll
  for (int t = 0; t < 2; ++t){
    int j = jp + t;
    float gi = gb[b][     j] + bias2[n0 +      j];
    float gf = gb[b][ 8 + j] + bias2[n0 +  8 + j];
    float gg = gb[b][16 + j] + bias2[n0 + 16 + j];
    float go = gb[b][24 + j] + bias2[n0 + 24 + j];
    float* cp = Cst + b*8 + j;
    float c = sigf(gf)*(*cp) + sigf(gi)*tanhf_(gg);
    float h = sigf(go)*tanhf_(c);
    *cp = c;
    hp.h[t] = (bf16)h;
  }
  const int u = bq*8 + jp;
  if (isA){
    *(u32*)(slotCur + (size_t)b*2560 + 512 + u) = hp.u;
  } else {
    *(u32*)(slotCur + (size_t)b*2560 + 1536 + u) = hp.u;
    *(u32*)(proj + ((size_t)(i-1)*64 + b)*1536 + u) = hp.u;   // dh(i-1) -> proj
  }
}

// ---------------- K2: attention (per step) ----------------------------------------
// 64 blocks x 256 thr; block = batch. Plain memory, kernel-boundary coherence.
__global__ __launch_bounds__(256)
void attn_step(const bf16* __restrict__ Wqb, const float* __restrict__ Wconv,
               const float* __restrict__ wlocTg, const float* __restrict__ vvp,
               const float* __restrict__ pm, const bf16* __restrict__ enc_bf,
               const float* __restrict__ alignPrev,   // out_attn base, step i-1
               bf16* __restrict__ slotCur, bf16* __restrict__ proj,
               float* __restrict__ out_attn, int i)
{
  const int tid = threadIdx.x;
  const int l = tid & 63, wv = tid >> 6;
  const int b = blockIdx.x;

  __shared__ __align__(16) bf16 ahs[1024];
  __shared__ float locb[200][32];
  __shared__ float awl[256];
  __shared__ float qp[256];
  __shared__ float qv[128];
  __shared__ float es[200];
  __shared__ float sred[4];
  __shared__ float wlocT[32][128];

  // stage: align(i-1), wlocT, ah(i)
  if (tid < 256) awl[tid] = 0.f;
  if (i > 0 && tid < 200) awl[tid] = alignPrev[((size_t)b*200 + (i-1))*200 + tid];
  for (int it = tid; it < 4096; it += 256)
    wlocT[it >> 7][it & 127] = wlocTg[it];
  if (tid < 128)
    *(bf16x8*)(&ahs[tid*8]) = *(const bf16x8*)(slotCur + (size_t)b*2560 + 512 + tid*8);
  __syncthreads();
  // conv1d(31)
  for (int it = tid; it < 6400; it += 256){
    int f = it & 31, tl = it >> 5;
    float s = 0.f;
    #pragma unroll
    for (int j = 0; j < 31; ++j){
      int tt = tl + j - 15;
      if ((unsigned)tt < 200u) s += awl[tt]*Wconv[f*31+j];
    }
    locb[tl][f] = s;
  }
  // q = ah @ Wq^T
  {
    int a = tid & 127, hf = tid >> 7;
    const bf16* wr = Wqb + (size_t)a*1024 + hf*512;
    float s = 0.f;
    for (int k2 = 0; k2 < 512; k2 += 8){
      bf16x8 x = *(const bf16x8*)(&ahs[hf*512 + k2]);
      bf16x8 y = *(const bf16x8*)(wr + k2);
      #pragma unroll
      for (int e = 0; e < 8; ++e) s += (float)x[e]*(float)y[e];
    }
    qp[tid] = s;
  }
  __syncthreads();
  if (tid < 128) qv[tid] = qp[tid] + qp[tid+128];
  __syncthreads();
  // energies
  for (int tl = wv; tl < 200; tl += 4){
    const float* pmrow = pm + ((size_t)b*200 + tl)*128;
    const float* lrow  = locb[tl];
    float s = 0.f;
    #pragma unroll
    for (int half = 0; half < 2; ++half){
      int a = l + half*64;
      float x = qv[a] + pmrow[a];
      #pragma unroll
      for (int f = 0; f < 32; ++f) x += lrow[f]*wlocT[f][a];
      s += vvp[a]*tanhf_(x);
    }
    #pragma unroll
    for (int o = 32; o; o >>= 1) s += __shfl_xor(s, o);
    if (l == 0) es[tl] = s;
  }
  __syncthreads();
  // softmax over 200
  {
    float e0 = (tid < 200) ? es[tid] : -3.0e38f;
    float m = e0;
    #pragma unroll
    for (int o = 32; o; o >>= 1) m = fmaxf(m, __shfl_xor(m, o));
    if (l == 0) sred[wv] = m;
    __syncthreads();
    m = fmaxf(fmaxf(sred[0],sred[1]), fmaxf(sred[2],sred[3]));
    float p = (tid < 200) ? __expf(e0 - m) : 0.f;
    float ss = p;
    #pragma unroll
    for (int o = 32; o; o >>= 1) ss += __shfl_xor(ss, o);
    __syncthreads();
    if (l == 0) sred[wv] = ss;
    __syncthreads();
    ss = sred[0]+sred[1]+sred[2]+sred[3];
    float aval = p / ss;
    if (tid < 200){
      awl[tid] = aval;
      out_attn[((size_t)b*200 + i)*200 + tid] = aval;
    }
  }
  __syncthreads();
  // context = align @ enc  -> slot i cols [0,512)
  {
    const u32* ep = (const u32*)(enc_bf + (size_t)b*102400) + tid;
    float x0=0.f, y0=0.f, x1=0.f, y1=0.f;
    #pragma unroll 8
    for (int t = 0; t < 200; t += 2){
      U2h w0; w0.u = ep[(size_t)t*256];
      U2h w1; w1.u = ep[(size_t)(t+1)*256];
      float al0 = awl[t], al1 = awl[t+1];
      x0 += al0*(float)w0.h[0]; y0 += al0*(float)w0.h[1];
      x1 += al1*(float)w1.h[0]; y1 += al1*(float)w1.h[1];
    }
    U2h cb; cb.h[0] = (bf16)(x0+x1); cb.h[1] = (bf16)(y0+y1);
    *((u32*)(slotCur + (size_t)b*2560) + tid) = cb.u;
    *((u32*)(proj + ((size_t)i*64 + b)*1536 + 1024) + tid) = cb.u;
  }
}

// ---------------- epilogue scatter -------------------------------------------------
__global__ void scatter_out(const float* __restrict__ mt_, float* __restrict__ out){
  int i = blockIdx.x*256 + threadIdx.x;
  const int NMEL = 12800*160;
  if (i < NMEL){
    int sb = i / 160, j = i % 160;
    int s = sb >> 6, b = sb & 63;
    int r = j / 80, mm = j % 80;
    out[((size_t)b*400 + 2*s + r)*80 + mm] = mt_[(size_t)sb*176 + j];
  } else if (i < NMEL + 12800){
    int sb = i - NMEL;
    int s = sb >> 6, b = sb & 63;
    float st = sigf(mt_[(size_t)sb*176 + 160]);
    float* so = out + 2048000;
    so[(size_t)b*400 + 2*s]     = st;
    so[(size_t)b*400 + 2*s + 1] = st;
  }
}

// ==================================================================================
extern "C" void kernel_launch(void* const* d_in, const int* in_sizes, int n_in,
                              void* d_out, int out_size, void* d_ws, size_t ws_size,
                              hipStream_t stream)
{
  const float* enc   = (const float*)d_in[0];
  const float* inp   = (const float*)d_in[1];
  const float* Wpre1 = (const float*)d_in[2];
  const float* bpre1 = (const float*)d_in[3];
  const float* Wpre2 = (const float*)d_in[4];
  const float* bpre2 = (const float*)d_in[5];
  const float* Wmem  = (const float*)d_in[6];
  const float* Wiha  = (const float*)d_in[7];
  const float* Whha  = (const float*)d_in[8];
  const float* biha  = (const float*)d_in[9];
  const float* bhha  = (const float*)d_in[10];
  const float* Wq    = (const float*)d_in[11];
  const float* Wconv = (const float*)d_in[12];
  const float* Wloc  = (const float*)d_in[13];
  const float* vv    = (const float*)d_in[14];
  const float* Wihd  = (const float*)d_in[15];
  const float* Whhd  = (const float*)d_in[16];
  const float* bihd  = (const float*)d_in[17];
  const float* bhhd  = (const float*)d_in[18];
  const float* Wmel  = (const float*)d_in[19];
  const float* bmel  = (const float*)d_in[20];
  const float* Wstop = (const float*)d_in[21];
  const float* bstop = (const float*)d_in[22];
  float* out = (float*)d_out;

  char* pp = (char*)d_ws;
  auto carve = [&](size_t bytes)->char*{
    char* r = (char*)(((uintptr_t)pp + 255) & ~(uintptr_t)255);
    pp = r + bytes;
    return r;
  };
  bf16*  enc_bf  = (bf16*) carve((size_t)64*200*512*2);
  float* pm      = (float*)carve((size_t)64*200*128*4);
  bf16*  decin   = (bf16*) carve((size_t)12800*96*2);
  bf16*  h1      = (bf16*) carve((size_t)12800*256*2);
  bf16*  pall    = (bf16*) carve((size_t)12800*256*2);
  bf16*  Wp1b    = (bf16*) carve((size_t)256*96*2);
  bf16*  Wp2b    = (bf16*) carve((size_t)256*256*2);
  bf16*  Wmemb   = (bf16*) carve((size_t)128*512*2);
  bf16*  Wqb     = (bf16*) carve((size_t)128*1024*2);
  bf16*  Wca     = (bf16*) carve((size_t)4096*KA*2);
  bf16*  Wcd2    = (bf16*) carve((size_t)4096*KD*2);
  bf16*  Wmc     = (bf16*) carve((size_t)176*1536*2);
  float* biasa2  = (float*)carve(4096*4);
  float* biasd2  = (float*)carve(4096*4);
  float* bias176 = (float*)carve(176*4);
  float* wlocTg  = (float*)carve(4096*4);
  bf16*  proj    = (bf16*) carve((size_t)12800*1536*2);
  float* meltmp  = (float*)carve((size_t)12800*176*4);
  // zeroed-every-launch block: cell states
  float* aC  = (float*)carve((size_t)128*64*8*4);
  float* dC  = (float*)carve((size_t)128*64*8*4);
  size_t zbytes = (size_t)((char*)dC + (size_t)128*64*8*4 - (char*)aC);
  // write-once activation ring: 202 slots of [64][2560] bf16
  bf16*  ring = (bf16*)carve((size_t)202*SLOT*2);
  hipMemsetAsync(aC, 0, zbytes, stream);
  hipMemsetAsync(ring, 0, (size_t)2*SLOT*2, stream);   // zero slots -1 and 0

  // ---- prologue: conversions / packing ----
  cvt_kernel<<<(6553600+255)/256,256,0,stream>>>(enc,   enc_bf, 6553600);
  cvt_kernel<<<(131072+255)/256, 256,0,stream>>>(Wq,    Wqb,    131072);
  cvt_kernel<<<(65536+255)/256,  256,0,stream>>>(Wmem,  Wmemb,  65536);
  cvt_kernel<<<(65536+255)/256,  256,0,stream>>>(Wpre2, Wp2b,   65536);
  cvt_pad_kernel<<<(256*96+255)/256,256,0,stream>>>(Wpre1, Wp1b, 256, 80, 96);
  build_wa_pack<<<(4096*1792+255)/256,256,0,stream>>>(Wiha, Whha, Wca);
  build_wd_pack<<<(4096*2560+255)/256,256,0,stream>>>(Wihd, Whhd, Wcd2);
  build_wmelcat<<<(176*1536+255)/256,256,0,stream>>>(Wmel, Wstop, Wmc);
  build_misc2<<<(8368+4096+255)/256,256,0,stream>>>(biha,bhha,biasa2, bihd,bhhd,biasd2,
                                                    bmel,bstop,bias176, Wloc, wlocTg);
  build_decin<<<(12800*96+255)/256,256,0,stream>>>(inp, decin);

  // ---- prologue: batched GEMMs ----
  gemm_k<1,1><<<800,256,0,stream>>>(decin, Wp1b, bpre1, nullptr, h1, 12800,256,96, 200);
  gemm_k<1,1><<<800,256,0,stream>>>(h1, Wp2b, bpre2, nullptr, pall, 12800,256,256, 200);
  gemm_k<0,0><<<400,256,0,stream>>>(enc_bf, Wmemb, nullptr, pm, nullptr, 12800,128,512, 200);

  // ---- per-step kernels: coherence via kernel boundaries, no barriers/atomics ----
  float* out_attn = out + 2073600;
  for (int i = 0; i <= STEPS; ++i){
    const bf16* slotPrev = ring + (size_t)i*SLOT;
    bf16*       slotCur  = ring + (size_t)(i+1)*SLOT;
    gates_step<<<256,256,0,stream>>>(pall, Wca, Wcd2, biasa2, biasd2,
                                     slotPrev, slotCur, aC, dC, proj,
                                     i, i < STEPS ? 1 : 0, i > 0 ? 1 : 0);
    if (i < STEPS)
      attn_step<<<64,256,0,stream>>>(Wqb, Wconv, wlocTg, vv, pm, enc_bf,
                                     out_attn, slotCur, proj, out_attn, i);
  }

  // ---- epilogue: mel/stop projection + scatter ----
  gemm_k<0,0><<<550,256,0,stream>>>(proj, Wmc, bias176, meltmp, nullptr, 12800,176,1536, 200);
  scatter_out<<<(12800*160+12800+255)/256,256,0,stream>>>(meltmp, out);
}

// Round 15
// 19739.886 us; speedup vs baseline: 1.5144x; 1.4458x over previous
//
#include <hip/hip_runtime.h>
#include <hip/hip_bf16.h>
#include <stdint.h>

// Dims
#define STEPS  200
#define KA     1792   // p(256) + ctx(512) + ah(1024)
#define KD     2560   // ctx(512) + ah(1024) + dh(1024)  (ring order)
#define SLOT   (64*2560)        // ring slot elements (bf16)

using bf16 = __bf16;
typedef __bf16 bf16x8 __attribute__((ext_vector_type(8)));
typedef float  f32x4  __attribute__((ext_vector_type(4)));
typedef unsigned int       u32;
typedef unsigned long long u64;

union U2h { u32 u; bf16 h[2]; };

#define MFMA16(a,b,c) __builtin_amdgcn_mfma_f32_16x16x32_bf16((a),(b),(c),0,0,0)

__device__ __forceinline__ float sigf(float x){ return 1.f/(1.f+__expf(-x)); }
__device__ __forceinline__ float tanhf_(float x){
  float ax = fabsf(x);
  float e  = __expf(-2.f*ax);
  float t  = (1.f-e)/(1.f+e);
  return x < 0.f ? -t : t;
}

// ---------------- prologue conversion kernels ----------------
__global__ void cvt_kernel(const float* __restrict__ s, bf16* __restrict__ d, int n){
  int i = blockIdx.x*256 + threadIdx.x;
  if (i < n) d[i] = (bf16)s[i];
}
__global__ void cvt_pad_kernel(const float* __restrict__ s, bf16* __restrict__ d,
                               int rows, int cin, int cout){
  int i = blockIdx.x*256 + threadIdx.x;
  if (i >= rows*cout) return;
  int r = i / cout, c = i % cout;
  d[i] = (bf16)(c < cin ? s[(size_t)r*cin + c] : 0.f);
}
// A-weights: packed rows r = q*32 + g*8 + j  <-  orig g*1024 + q*8 + j ; K=[p768|ah1024]
__global__ void build_wa_pack(const float* __restrict__ Wiha, const float* __restrict__ Whha,
                              bf16* __restrict__ d){
  int i = blockIdx.x*256 + threadIdx.x;
  if (i >= 4096*1792) return;
  int r = i / 1792, k = i % 1792;
  int q = r >> 5, g = (r >> 3) & 3, j = r & 7;
  int orig = g*1024 + q*8 + j;
  float v = (k < 768) ? Wiha[(size_t)orig*768 + k] : Whha[(size_t)orig*1024 + (k - 768)];
  d[i] = (bf16)v;
}
// D-weights: packed rows (same permute); K-order [ctx512 | ah1024 | dh1024]
__global__ void build_wd_pack(const float* __restrict__ Wihd, const float* __restrict__ Whhd,
                              bf16* __restrict__ d){
  int i = blockIdx.x*256 + threadIdx.x;
  if (i >= 4096*2560) return;
  int r = i / 2560, k = i % 2560;
  int q = r >> 5, g = (r >> 3) & 3, j = r & 7;
  int orig = g*1024 + q*8 + j;
  float v;
  if (k < 512)        v = Wihd[(size_t)orig*1536 + 1024 + k];
  else if (k < 1536)  v = Wihd[(size_t)orig*1536 + (k - 512)];
  else                v = Whhd[(size_t)orig*1024 + (k - 1536)];
  d[i] = (bf16)v;
}
__global__ void build_wmelcat(const float* __restrict__ Wmel, const float* __restrict__ Wstop,
                              bf16* __restrict__ d){
  int i = blockIdx.x*256 + threadIdx.x;
  if (i >= 176*1536) return;
  int r = i / 1536, c = i % 1536;
  float v = (r < 160) ? Wmel[(size_t)r*1536 + c] : (r == 160 ? Wstop[c] : 0.f);
  d[i] = (bf16)v;
}
// packed biases + mel bias + transposed Wloc
__global__ void build_misc2(const float* biha, const float* bhha, float* biasa2,
                            const float* bihd, const float* bhhd, float* biasd2,
                            const float* bmel, const float* bstop, float* bias176,
                            const float* Wloc, float* wlocT){
  int i = blockIdx.x*256 + threadIdx.x;
  if (i < 4096){
    int q = i >> 5, g = (i >> 3) & 3, j = i & 7;
    int orig = g*1024 + q*8 + j;
    biasa2[i] = biha[orig] + bhha[orig];
  } else if (i < 8192){
    int r = i - 4096;
    int q = r >> 5, g = (r >> 3) & 3, j = r & 7;
    int orig = g*1024 + q*8 + j;
    biasd2[r] = bihd[orig] + bhhd[orig];
  } else if (i < 8192+176){
    int j = i - 8192;
    bias176[j] = (j < 160) ? bmel[j] : (j == 160 ? bstop[0] : 0.f);
  } else if (i < 8192+176+4096){
    int t = i - 8368;                 // t = f*128 + a
    int f = t >> 7, a = t & 127;
    wlocT[t] = Wloc[a*32 + f];
  }
}
__global__ void build_decin(const float* __restrict__ inp, bf16* __restrict__ d){
  int i = blockIdx.x*256 + threadIdx.x;
  if (i >= 12800*96) return;
  int row = i / 96, c = i % 96;
  int s = row >> 6, b = row & 63;
  float v = 0.f;
  if (c < 80 && s > 0) v = inp[((size_t)b*400 + (2*s - 1))*80 + c];
  d[i] = (bf16)v;
}

// ---------------- generic MFMA GEMM (prologue/epilogue batched use) ----------------
template<int ACT, int OBF>
__global__ __launch_bounds__(256)
void gemm_k(const bf16* __restrict__ A, const bf16* __restrict__ Bm,
            const float* __restrict__ bias, float* __restrict__ Cf,
            bf16* __restrict__ Cb, int M, int N, int K, int MT)
{
  int wid = blockIdx.x*4 + (threadIdx.x >> 6);
  if (wid >= MT*(N >> 4)) return;
  int wm = wid % MT, wn = wid / MT;
  int l = threadIdx.x & 63, lo = l & 15, hi = l >> 4;
  const bf16* Bp = Bm + (size_t)(wn*16 + lo)*K + hi*8;
  const bf16* Ap = A  + (size_t)(wm*64 + lo)*K + hi*8;
  f32x4 acc0 = {0,0,0,0}, acc1 = {0,0,0,0}, acc2 = {0,0,0,0}, acc3 = {0,0,0,0};
  for (int k = 0; k < K; k += 32){
    bf16x8 bb = *(const bf16x8*)(Bp + k);
    bf16x8 a0 = *(const bf16x8*)(Ap + k);
    bf16x8 a1 = *(const bf16x8*)(Ap + (size_t)16*K + k);
    bf16x8 a2 = *(const bf16x8*)(Ap + (size_t)32*K + k);
    bf16x8 a3 = *(const bf16x8*)(Ap + (size_t)48*K + k);
    acc0 = MFMA16(a0, bb, acc0);
    acc1 = MFMA16(a1, bb, acc1);
    acc2 = MFMA16(a2, bb, acc2);
    acc3 = MFMA16(a3, bb, acc3);
  }
  int n = wn*16 + lo;
  float bv = bias ? bias[n] : 0.f;
  int m0 = wm*64 + hi*4;
  #pragma unroll
  for (int mt = 0; mt < 4; ++mt){
    f32x4 av = (mt==0)?acc0:(mt==1)?acc1:(mt==2)?acc2:acc3;
    #pragma unroll
    for (int r = 0; r < 4; ++r){
      float v = av[r] + bv;
      if (ACT) v = fmaxf(v, 0.f);
      size_t idx = (size_t)(m0 + mt*16 + r)*N + n;
      if (OBF) Cb[idx] = (bf16)v; else Cf[idx] = v;
    }
  }
}

// ---------------- K1: fused gate-GEMM + LSTM cell, 16 waves/CU --------------------
// 256 blocks x 1024 thr. Blocks 0-127: attn-LSTM(i). Blocks 128-255: dec-LSTM(i-1).
// Wave (kq = wv&3, m-group = wv>>2): K split 4-ways -> LDS partials -> reduce in
// cell update. 4x memory concurrency vs the 256-thread version (R15 experiment).
__global__ __launch_bounds__(1024)
void gates_step(const bf16* __restrict__ pall,
                const bf16* __restrict__ Wa, const bf16* __restrict__ Wd2,
                const float* __restrict__ biasa2, const float* __restrict__ biasd2,
                const bf16* __restrict__ slotPrev, bf16* __restrict__ slotCur,
                float* __restrict__ aC, float* __restrict__ dC,
                bf16* __restrict__ proj, int i, int doA, int doD)
{
  const bool isA = blockIdx.x < 128;
  if (isA ? !doA : !doD) return;
  const int tid = threadIdx.x;
  const int l = tid & 63, lo = l & 15, hi = l >> 4;
  const int wv = tid >> 6;            // 0..15
  const int kq = wv & 3;              // K-quarter
  const int m0 = (wv >> 2) * 16;      // batch-row group
  const int bq = isA ? blockIdx.x : blockIdx.x - 128;
  const int n0 = bq * 32;
  const int K  = isA ? KA : KD;
  const int JQ = isA ? 14 : 20;       // (K/4)/32
  const bf16* Wg = isA ? Wa : Wd2;
  const float* bias2 = isA ? biasa2 : biasd2;
  float* Cst = (isA ? aC : dC) + (size_t)bq*64*8;

  __shared__ float red[4][64][33];    // per-kq partials, +1 pad

  const bf16* Wp0  = Wg + (size_t)(n0 +      lo)*K + hi*8;
  const bf16* Wp1  = Wg + (size_t)(n0 + 16 + lo)*K + hi*8;
  const bf16* Xrow = slotPrev + (size_t)(m0 + lo)*2560 + hi*8;
  const bf16* Prow = pall + ((size_t)i*64 + m0 + lo)*256 + hi*8;
  const int kbase = kq * (K >> 2);
  f32x4 acc0 = {0,0,0,0}, acc1 = {0,0,0,0};
  #pragma unroll 4
  for (int jj = 0; jj < JQ; ++jj){
    int k = kbase + jj*32;
    const bf16* ap;
    if (isA) ap = (k < 256) ? (Prow + k) : (Xrow + (k - 256));
    else     ap = Xrow + k;
    bf16x8 a  = *(const bf16x8*)ap;
    bf16x8 b0 = *(const bf16x8*)(Wp0 + k);
    bf16x8 b1 = *(const bf16x8*)(Wp1 + k);
    acc0 = MFMA16(a, b0, acc0);
    acc1 = MFMA16(a, b1, acc1);
  }
  #pragma unroll
  for (int r = 0; r < 4; ++r){
    red[kq][m0 + hi*4 + r][lo]      = acc0[r];
    red[kq][m0 + hi*4 + r][16 + lo] = acc1[r];
  }
  __syncthreads();
  // cell update: 256 threads -> (batch b = tid>>2, unit pair jp = (tid&3)*2)
  if (tid < 256){
    const int b  = tid >> 2;
    const int jp = (tid & 3)*2;
    U2h hp;
    #pragma unroll
    for (int t = 0; t < 2; ++t){
      int j = jp + t;
      float gi = red[0][b][     j] + red[1][b][     j] + red[2][b][     j] + red[3][b][     j] + bias2[n0 +      j];
      float gf = red[0][b][ 8 + j] + red[1][b][ 8 + j] + red[2][b][ 8 + j] + red[3][b][ 8 + j] + bias2[n0 +  8 + j];
      float gg = red[0][b][16 + j] + red[1][b][16 + j] + red[2][b][16 + j] + red[3][b][16 + j] + bias2[n0 + 16 + j];
      float go = red[0][b][24 + j] + red[1][b][24 + j] + red[2][b][24 + j] + red[3][b][24 + j] + bias2[n0 + 24 + j];
      float* cp = Cst + b*8 + j;
      float c = sigf(gf)*(*cp) + sigf(gi)*tanhf_(gg);
      float h = sigf(go)*tanhf_(c);
      *cp = c;
      hp.h[t] = (bf16)h;
    }
    const int u = bq*8 + jp;
    if (isA){
      *(u32*)(slotCur + (size_t)b*2560 + 512 + u) = hp.u;
    } else {
      *(u32*)(slotCur + (size_t)b*2560 + 1536 + u) = hp.u;
      *(u32*)(proj + ((size_t)(i-1)*64 + b)*1536 + u) = hp.u;   // dh(i-1) -> proj
    }
  }
}

// ---------------- K2: attention, 16 waves/CU --------------------------------------
// 64 blocks x 1024 thr; block = batch. Plain memory, kernel-boundary coherence.
__global__ __launch_bounds__(1024)
void attn_step(const bf16* __restrict__ Wqb, const float* __restrict__ Wconv,
               const float* __restrict__ wlocTg, const float* __restrict__ vvp,
               const float* __restrict__ pm, const bf16* __restrict__ enc_bf,
               const float* __restrict__ alignPrev,   // out_attn base, step i-1
               bf16* __restrict__ slotCur, bf16* __restrict__ proj,
               float* __restrict__ out_attn, int i)
{
  const int tid = threadIdx.x;
  const int l = tid & 63, wv = tid >> 6;
  const int b = blockIdx.x;

  __shared__ __align__(16) bf16 ahs[1024];
  __shared__ float locb[200][32];
  __shared__ float awl[256];
  __shared__ float qp[1024];
  __shared__ float qv[128];
  __shared__ float es[200];
  __shared__ float sred[16];
  __shared__ float wlocT[32][128];
  __shared__ float credx[4][256];
  __shared__ float credy[4][256];

  // stage: align(i-1), wlocT, ah(i)
  if (tid < 256) awl[tid] = 0.f;
  if (i > 0 && tid < 200) awl[tid] = alignPrev[((size_t)b*200 + (i-1))*200 + tid];
  for (int it = tid; it < 4096; it += 1024)
    wlocT[it >> 7][it & 127] = wlocTg[it];
  if (tid < 128)
    *(bf16x8*)(&ahs[tid*8]) = *(const bf16x8*)(slotCur + (size_t)b*2560 + 512 + tid*8);
  __syncthreads();
  // conv1d(31)
  for (int it = tid; it < 6400; it += 1024){
    int f = it & 31, tl = it >> 5;
    float s = 0.f;
    #pragma unroll
    for (int j = 0; j < 31; ++j){
      int tt = tl + j - 15;
      if ((unsigned)tt < 200u) s += awl[tt]*Wconv[f*31+j];
    }
    locb[tl][f] = s;
  }
  // q = ah @ Wq^T  (8 segments of 128 per attn dim)
  {
    int a = tid & 127, seg = tid >> 7;
    const bf16* wr = Wqb + (size_t)a*1024 + seg*128;
    float s = 0.f;
    #pragma unroll
    for (int k2 = 0; k2 < 128; k2 += 8){
      bf16x8 x = *(const bf16x8*)(&ahs[seg*128 + k2]);
      bf16x8 y = *(const bf16x8*)(wr + k2);
      #pragma unroll
      for (int e = 0; e < 8; ++e) s += (float)x[e]*(float)y[e];
    }
    qp[tid] = s;
  }
  __syncthreads();
  if (tid < 128){
    float s = 0.f;
    #pragma unroll
    for (int sg = 0; sg < 8; ++sg) s += qp[tid + sg*128];
    qv[tid] = s;
  }
  __syncthreads();
  // energies (16 waves over 200 rows)
  for (int tl = wv; tl < 200; tl += 16){
    const float* pmrow = pm + ((size_t)b*200 + tl)*128;
    const float* lrow  = locb[tl];
    float s = 0.f;
    #pragma unroll
    for (int half = 0; half < 2; ++half){
      int a = l + half*64;
      float x = qv[a] + pmrow[a];
      #pragma unroll
      for (int f = 0; f < 32; ++f) x += lrow[f]*wlocT[f][a];
      s += vvp[a]*tanhf_(x);
    }
    #pragma unroll
    for (int o = 32; o; o >>= 1) s += __shfl_xor(s, o);
    if (l == 0) es[tl] = s;
  }
  __syncthreads();
  // softmax over 200 (waves 0-3 carry data; others contribute identities)
  {
    float e0 = (tid < 200) ? es[tid] : -3.0e38f;
    float m = e0;
    #pragma unroll
    for (int o = 32; o; o >>= 1) m = fmaxf(m, __shfl_xor(m, o));
    if (l == 0) sred[wv] = m;
    __syncthreads();
    m = fmaxf(fmaxf(sred[0],sred[1]), fmaxf(sred[2],sred[3]));
    float p = (tid < 200) ? __expf(e0 - m) : 0.f;
    float ss = p;
    #pragma unroll
    for (int o = 32; o; o >>= 1) ss += __shfl_xor(ss, o);
    __syncthreads();
    if (l == 0) sred[wv] = ss;
    __syncthreads();
    ss = sred[0]+sred[1]+sred[2]+sred[3];
    float aval = p / ss;
    if (tid < 200){
      awl[tid] = aval;
      out_attn[((size_t)b*200 + i)*200 + tid] = aval;
    }
  }
  __syncthreads();
  // context = align @ enc : 4 t-quarters x 256 u32-cols, LDS reduce
  {
    const int col = tid & 255, tq = tid >> 8;
    const u32* ep = (const u32*)(enc_bf + (size_t)b*102400) + col;
    float x0 = 0.f, y0 = 0.f;
    const int t0 = tq*50;
    #pragma unroll 5
    for (int t = t0; t < t0 + 50; ++t){
      U2h w; w.u = ep[(size_t)t*256];
      float al = awl[t];
      x0 += al*(float)w.h[0];
      y0 += al*(float)w.h[1];
    }
    credx[tq][col] = x0;
    credy[tq][col] = y0;
  }
  __syncthreads();
  if (tid < 256){
    float sx = credx[0][tid]+credx[1][tid]+credx[2][tid]+credx[3][tid];
    float sy = credy[0][tid]+credy[1][tid]+credy[2][tid]+credy[3][tid];
    U2h cb; cb.h[0] = (bf16)sx; cb.h[1] = (bf16)sy;
    *((u32*)(slotCur + (size_t)b*2560) + tid) = cb.u;
    *((u32*)(proj + ((size_t)i*64 + b)*1536 + 1024) + tid) = cb.u;
  }
}

// ---------------- epilogue scatter -------------------------------------------------
__global__ void scatter_out(const float* __restrict__ mt_, float* __restrict__ out){
  int i = blockIdx.x*256 + threadIdx.x;
  const int NMEL = 12800*160;
  if (i < NMEL){
    int sb = i / 160, j = i % 160;
    int s = sb >> 6, b = sb & 63;
    int r = j / 80, mm = j % 80;
    out[((size_t)b*400 + 2*s + r)*80 + mm] = mt_[(size_t)sb*176 + j];
  } else if (i < NMEL + 12800){
    int sb = i - NMEL;
    int s = sb >> 6, b = sb & 63;
    float st = sigf(mt_[(size_t)sb*176 + 160]);
    float* so = out + 2048000;
    so[(size_t)b*400 + 2*s]     = st;
    so[(size_t)b*400 + 2*s + 1] = st;
  }
}

// ==================================================================================
extern "C" void kernel_launch(void* const* d_in, const int* in_sizes, int n_in,
                              void* d_out, int out_size, void* d_ws, size_t ws_size,
                              hipStream_t stream)
{
  const float* enc   = (const float*)d_in[0];
  const float* inp   = (const float*)d_in[1];
  const float* Wpre1 = (const float*)d_in[2];
  const float* bpre1 = (const float*)d_in[3];
  const float* Wpre2 = (const float*)d_in[4];
  const float* bpre2 = (const float*)d_in[5];
  const float* Wmem  = (const float*)d_in[6];
  const float* Wiha  = (const float*)d_in[7];
  const float* Whha  = (const float*)d_in[8];
  const float* biha  = (const float*)d_in[9];
  const float* bhha  = (const float*)d_in[10];
  const float* Wq    = (const float*)d_in[11];
  const float* Wconv = (const float*)d_in[12];
  const float* Wloc  = (const float*)d_in[13];
  const float* vv    = (const float*)d_in[14];
  const float* Wihd  = (const float*)d_in[15];
  const float* Whhd  = (const float*)d_in[16];
  const float* bihd  = (const float*)d_in[17];
  const float* bhhd  = (const float*)d_in[18];
  const float* Wmel  = (const float*)d_in[19];
  const float* bmel  = (const float*)d_in[20];
  const float* Wstop = (const float*)d_in[21];
  const float* bstop = (const float*)d_in[22];
  float* out = (float*)d_out;

  char* pp = (char*)d_ws;
  auto carve = [&](size_t bytes)->char*{
    char* r = (char*)(((uintptr_t)pp + 255) & ~(uintptr_t)255);
    pp = r + bytes;
    return r;
  };
  bf16*  enc_bf  = (bf16*) carve((size_t)64*200*512*2);
  float* pm      = (float*)carve((size_t)64*200*128*4);
  bf16*  decin   = (bf16*) carve((size_t)12800*96*2);
  bf16*  h1      = (bf16*) carve((size_t)12800*256*2);
  bf16*  pall    = (bf16*) carve((size_t)12800*256*2);
  bf16*  Wp1b    = (bf16*) carve((size_t)256*96*2);
  bf16*  Wp2b    = (bf16*) carve((size_t)256*256*2);
  bf16*  Wmemb   = (bf16*) carve((size_t)128*512*2);
  bf16*  Wqb     = (bf16*) carve((size_t)128*1024*2);
  bf16*  Wca     = (bf16*) carve((size_t)4096*KA*2);
  bf16*  Wcd2    = (bf16*) carve((size_t)4096*KD*2);
  bf16*  Wmc     = (bf16*) carve((size_t)176*1536*2);
  float* biasa2  = (float*)carve(4096*4);
  float* biasd2  = (float*)carve(4096*4);
  float* bias176 = (float*)carve(176*4);
  float* wlocTg  = (float*)carve(4096*4);
  bf16*  proj    = (bf16*) carve((size_t)12800*1536*2);
  float* meltmp  = (float*)carve((size_t)12800*176*4);
  // zeroed-every-launch block: cell states
  float* aC  = (float*)carve((size_t)128*64*8*4);
  float* dC  = (float*)carve((size_t)128*64*8*4);
  size_t zbytes = (size_t)((char*)dC + (size_t)128*64*8*4 - (char*)aC);
  // write-once activation ring: 202 slots of [64][2560] bf16
  bf16*  ring = (bf16*)carve((size_t)202*SLOT*2);
  hipMemsetAsync(aC, 0, zbytes, stream);
  hipMemsetAsync(ring, 0, (size_t)2*SLOT*2, stream);   // zero slots -1 and 0

  // ---- prologue: conversions / packing ----
  cvt_kernel<<<(6553600+255)/256,256,0,stream>>>(enc,   enc_bf, 6553600);
  cvt_kernel<<<(131072+255)/256, 256,0,stream>>>(Wq,    Wqb,    131072);
  cvt_kernel<<<(65536+255)/256,  256,0,stream>>>(Wmem,  Wmemb,  65536);
  cvt_kernel<<<(65536+255)/256,  256,0,stream>>>(Wpre2, Wp2b,   65536);
  cvt_pad_kernel<<<(256*96+255)/256,256,0,stream>>>(Wpre1, Wp1b, 256, 80, 96);
  build_wa_pack<<<(4096*1792+255)/256,256,0,stream>>>(Wiha, Whha, Wca);
  build_wd_pack<<<(4096*2560+255)/256,256,0,stream>>>(Wihd, Whhd, Wcd2);
  build_wmelcat<<<(176*1536+255)/256,256,0,stream>>>(Wmel, Wstop, Wmc);
  build_misc2<<<(8368+4096+255)/256,256,0,stream>>>(biha,bhha,biasa2, bihd,bhhd,biasd2,
                                                    bmel,bstop,bias176, Wloc, wlocTg);
  build_decin<<<(12800*96+255)/256,256,0,stream>>>(inp, decin);

  // ---- prologue: batched GEMMs ----
  gemm_k<1,1><<<800,256,0,stream>>>(decin, Wp1b, bpre1, nullptr, h1, 12800,256,96, 200);
  gemm_k<1,1><<<800,256,0,stream>>>(h1, Wp2b, bpre2, nullptr, pall, 12800,256,256, 200);
  gemm_k<0,0><<<400,256,0,stream>>>(enc_bf, Wmemb, nullptr, pm, nullptr, 12800,128,512, 200);

  // ---- per-step kernels: coherence via kernel boundaries, 16 waves/CU ----
  float* out_attn = out + 2073600;
  for (int i = 0; i <= STEPS; ++i){
    const bf16* slotPrev = ring + (size_t)i*SLOT;
    bf16*       slotCur  = ring + (size_t)(i+1)*SLOT;
    gates_step<<<256,1024,0,stream>>>(pall, Wca, Wcd2, biasa2, biasd2,
                                      slotPrev, slotCur, aC, dC, proj,
                                      i, i < STEPS ? 1 : 0, i > 0 ? 1 : 0);
    if (i < STEPS)
      attn_step<<<64,1024,0,stream>>>(Wqb, Wconv, wlocTg, vv, pm, enc_bf,
                                      out_attn, slotCur, proj, out_attn, i);
  }

  // ---- epilogue: mel/stop projection + scatter ----
  gemm_k<0,0><<<550,256,0,stream>>>(proj, Wmc, bias176, meltmp, nullptr, 12800,176,1536, 200);
  scatter_out<<<(12800*160+12800+255)/256,256,0,stream>>>(meltmp, out);
}